// Round 6
// baseline (3059.338 us; speedup 1.0000x reference)
//
#include <hip/hip_runtime.h>
#include <stdint.h>

// Farthest Point Sampling, B=8, N=131072, npoint=1024.
// 8 batches x 32 WGs x 256 threads (all 256 CUs), BARRIER-FREE main loop:
// each wave owns 1024 contiguous points, publishes its own padded slot
// (128 slots/batch), and polls/reduces all 128 slots itself. No intra-WG
// coupling after the one-time LDS fill.
// Coords are hoisted LDS->VGPR before the loop: ds_read results are NOT
// rematerializable (unlike the global loads rounds 2-4 fought), so they
// stay register-resident; the update phase is pure register VALU.
// Sync: tagged, parity-double-buffered, cache-line-padded slots in d_ws,
// relaxed agent-scope atomics (the 64-bit slot word is the whole payload).

#define NPTS        131072
#define NBATCH      8
#define WGB         32          // workgroups per batch
#define THREADS     256
#define PPW         4096        // points per WG
#define NSLOT       (WGB * 4)   // 128 per-WAVE slots per batch
#define SLOT_STRIDE 16          // ULLs per slot = 128 B (own cache line)
#define BIGDIST     1e10f

__global__ __launch_bounds__(THREADS, 1) void fps_kernel(
        const float* __restrict__ xyz,          // [B, N, 3]
        int* __restrict__ out,                  // [B, npoint]
        unsigned long long* __restrict__ slots, // [2][NBATCH][NSLOT][SLOT_STRIDE]
        int npoint)
{
    const int bid  = blockIdx.x;
    const int b    = bid & (NBATCH - 1);  // batch; its 32 WGs on one XCD (heuristic)
    const int w    = bid >> 3;            // 0..31 WG-within-batch
    const int tid  = threadIdx.x;
    const int lane = tid & 63;
    const int v    = tid >> 6;            // wave 0..3

    const float* base = xyz + (size_t)b * NPTS * 3;
    const int q0 = w * PPW;               // first batch-point of this WG

    // ---- LDS staging (only vehicle to get coords into VGPRs) ----
    __shared__ __align__(16) float x_lds[PPW];
    __shared__ __align__(16) float y_lds[PPW];
    __shared__ __align__(16) float z_lds[PPW];

    #pragma unroll
    for (int j = 0; j < 16; ++j) {
        int q = tid + 256 * j;                      // 0..4095 within WG
        const float* p = base + (size_t)(q0 + q) * 3;
        x_lds[q] = p[0];
        y_lds[q] = p[1];
        z_lds[q] = p[2];
    }
    __syncthreads();   // the ONLY barrier in the kernel

    // ---- hoist this lane's 16 points LDS -> registers (12x ds_read_b128) ----
    // lane owns q = 1024*v + 4*lane + 256*g + e  (g,e in 0..3), ascending in (g,e)
    const int pbase = q0 + 1024 * v + 4 * lane;     // batch index of (g=0,e=0)
    float4 X[4], Y[4], Z[4];
    #pragma unroll
    for (int g = 0; g < 4; ++g) {
        const int qg = 1024 * v + 4 * lane + 256 * g;
        X[g] = *reinterpret_cast<const float4*>(&x_lds[qg]);
        Y[g] = *reinterpret_cast<const float4*>(&y_lds[qg]);
        Z[g] = *reinterpret_cast<const float4*>(&z_lds[qg]);
    }
    float dist[16];
    #pragma unroll
    for (int j = 0; j < 16; ++j) dist[j] = BIGDIST;

    // initial centroid = point 0 of this batch
    float cx = base[0], cy = base[1], cz = base[2];

    if (w == 0 && tid == 0) out[b * npoint + 0] = 0;

    const size_t PAR = (size_t)NBATCH * NSLOT * SLOT_STRIDE;   // parity block (ULLs)
    unsigned long long* sbase = slots + (size_t)b * NSLOT * SLOT_STRIDE;
    const int sid = (w << 2) | v;                               // this wave's slot

    for (int i = 0; i < npoint - 1; ++i) {
        // ---- distance min-update + per-lane argmax (pure register VALU) ----
        float bv = -1.0f; int boff = 0;   // boff = 256*g + e of best
        {
            #pragma clang fp contract(off)
            #pragma unroll
            for (int g = 0; g < 4; ++g) {
                float xs[4] = { X[g].x, X[g].y, X[g].z, X[g].w };
                float ys[4] = { Y[g].x, Y[g].y, Y[g].z, Y[g].w };
                float zs[4] = { Z[g].x, Z[g].y, Z[g].z, Z[g].w };
                #pragma unroll
                for (int e = 0; e < 4; ++e) {
                    const int j = 4 * g + e;
                    float dx = xs[e] - cx, dy = ys[e] - cy, dz = zs[e] - cz;
                    float d  = dx*dx + dy*dy + dz*dz;   // mul/add order matches np ref
                    float nd = fminf(dist[j], d);
                    dist[j]  = nd;
                    if (nd > bv) { bv = nd; boff = 256 * g + e; }  // strict >: first max
                }
            }
        }
        // pack: [63:32] float bits (non-neg -> order-preserving)
        //       [16:0]  131071 - idx  (bigger packed == smaller idx on tie)
        //       [31:22] hold the tag at publish time (zero here)
        unsigned long long pk =
              ((unsigned long long)__float_as_uint(bv) << 32)
            | (unsigned long long)(0x1FFFFu - (unsigned)(pbase + boff));

        // ---- wave butterfly max on packed u64 (all lanes end with wave max) ----
        #pragma unroll
        for (int m = 32; m >= 1; m >>= 1) {
            unsigned long long o = __shfl_xor(pk, m);
            if (o > pk) pk = o;
        }

        unsigned long long* sb = sbase + ((i & 1) ? PAR : (size_t)0);
        const unsigned tag = (unsigned)(i + 1);   // 1..1023, fits 10 bits, never 0

        // ---- publish this wave's partial (lane 0) ----
        if (lane == 0) {
            __hip_atomic_store(sb + (size_t)sid * SLOT_STRIDE,
                               pk | ((unsigned long long)tag << 22),
                               __ATOMIC_RELAXED, __HIP_MEMORY_SCOPE_AGENT);
        }

        // ---- poll: each lane covers 2 of the 128 slots ----
        unsigned long long* a0 = sb + (size_t)(2 * lane)     * SLOT_STRIDE;
        unsigned long long* a1 = sb + (size_t)(2 * lane + 1) * SLOT_STRIDE;
        unsigned long long s0 = 0, s1 = 0;
        bool ok0 = false, ok1 = false;
        do {
            if (!ok0) {
                s0 = __hip_atomic_load(a0, __ATOMIC_RELAXED, __HIP_MEMORY_SCOPE_AGENT);
                ok0 = ((unsigned)(s0 >> 22) & 1023u) == tag;
            }
            if (!ok1) {
                s1 = __hip_atomic_load(a1, __ATOMIC_RELAXED, __HIP_MEMORY_SCOPE_AGENT);
                ok1 = ((unsigned)(s1 >> 22) & 1023u) == tag;
            }
        } while (!(ok0 && ok1));

        unsigned long long m2 = (s0 > s1) ? s0 : s1;
        // speculative candidate-coords fetch (overlaps the butterfly)
        int idx_l = (int)(0x1FFFFu - (unsigned)(m2 & 0x1FFFFu));
        const float* cp = base + (size_t)idx_l * 3;
        float ccx = cp[0], ccy = cp[1], ccz = cp[2];

        // ---- butterfly max over the 64 lane-candidates -> global winner ----
        unsigned long long mx = m2;
        #pragma unroll
        for (int m = 32; m >= 1; m >>= 1) {
            unsigned long long o = __shfl_xor(mx, m);
            if (o > mx) mx = o;
        }
        unsigned long long ball = __ballot(m2 == mx);
        int winlane = __ffsll(ball) - 1;
        cx = __shfl(ccx, winlane);
        cy = __shfl(ccy, winlane);
        cz = __shfl(ccz, winlane);
        int wix = __shfl(idx_l, winlane);

        if (w == 0 && tid == 0) out[b * npoint + (i + 1)] = wix;
    }
}

extern "C" void kernel_launch(void* const* d_in, const int* in_sizes, int n_in,
                              void* d_out, int out_size, void* d_ws, size_t ws_size,
                              hipStream_t stream) {
    const float* xyz = (const float*)d_in[0];
    int* out = (int*)d_out;
    unsigned long long* slots = (unsigned long long*)d_ws;
    const int npoint = out_size / NBATCH;   // 1024

    // Clear slot region (256 KB) so stale/poisoned tags can never match tag>=1.
    hipMemsetAsync(d_ws, 0,
                   (size_t)2 * NBATCH * NSLOT * SLOT_STRIDE * sizeof(unsigned long long),
                   stream);

    dim3 grid(NBATCH * WGB);   // 256 WGs <= 256 CUs -> all co-resident, spin-sync safe
    dim3 block(THREADS);
    fps_kernel<<<grid, block, 0, stream>>>(xyz, out, slots, npoint);
}

// Round 7
// 2892.894 us; speedup vs baseline: 1.0575x; 1.0575x over previous
//
#include <hip/hip_runtime.h>
#include <stdint.h>

// Farthest Point Sampling, B=8, N=131072, npoint=1024.
// 8 batches x 32 WGs x 256 threads (all 256 CUs). r5 topology (32 WG-slots,
// one polling wave per WG, 2 barriers/iter) -- r6 proved per-wave slots
// multiply fabric traffic 3x and regress.
// Fix 1: winner COORDS travel inside the slot (4 self-tagged u64 words), so
//   the serial per-iter HBM gather of base[idx*3] (r5's hidden 0.4-0.9us,
//   FETCH_SIZE 36MB) is eliminated; publisher reads candidate coords from
//   its own LDS tile.
// Fix 2: coords pinned in VGPRs as named scalars defined by opaque asm --
//   arrays alloca'd to scratch (r3) and plain SSA got rematerialized (r4/r6);
//   an asm def cannot be remat'd and ~90 live VGPRs fit the (256,1) budget.
// Sync: tagged, parity-double-buffered, cache-line-padded slots in d_ws,
// relaxed agent-scope atomics (every word is individually self-tagged).

#define NPTS        131072
#define NBATCH      8
#define WGB         32          // workgroups per batch
#define THREADS     256
#define PPW         4096        // points per WG
#define PPL         16          // points per lane (PPW/THREADS)
#define SLOT_STRIDE 16          // u64s per slot = 128 B (own cache line)
#define BIGDIST     1e10f

typedef unsigned long long u64;

#define LIST16(M) M(0) M(1) M(2) M(3) M(4) M(5) M(6) M(7) \
                  M(8) M(9) M(10) M(11) M(12) M(13) M(14) M(15)

__global__ __launch_bounds__(THREADS, 1) void fps_kernel(
        const float* __restrict__ xyz,   // [B, N, 3]
        int* __restrict__ out,           // [B, npoint]
        u64* __restrict__ slots,         // [2][NBATCH][WGB][SLOT_STRIDE]
        int npoint)
{
    const int bid  = blockIdx.x;
    const int b    = bid & (NBATCH - 1);  // batch; its 32 WGs on one XCD (heuristic)
    const int w    = bid >> 3;            // 0..31 WG-within-batch
    const int tid  = threadIdx.x;
    const int lane = tid & 63;
    const int v    = tid >> 6;            // wave 0..3

    const float* base = xyz + (size_t)b * NPTS * 3;
    const int q0 = w * PPW;               // first batch-point of this WG

    __shared__ __align__(16) float x_lds[PPW];   // coord tile (also serves
    __shared__ __align__(16) float y_lds[PPW];   //  publisher's winner lookup)
    __shared__ __align__(16) float z_lds[PPW];
    __shared__ u64   s_w[THREADS / 64];
    __shared__ float s_c[3];
    __shared__ int   s_f;

    #pragma unroll
    for (int j = 0; j < 16; ++j) {
        int q = tid + 256 * j;                      // 0..4095 within WG
        const float* p = base + (size_t)(q0 + q) * 3;
        x_lds[q] = p[0];
        y_lds[q] = p[1];
        z_lds[q] = p[2];
    }
    __syncthreads();

    const int qb    = tid * PPL;          // my 16 consecutive LDS-local points
    const int pbase = q0 + qb;            // batch-global index of my j=0

    // ---- hoist to named scalars, then pin with an opaque asm def ----
    #define DECLC(j) float x##j = x_lds[qb + j], y##j = y_lds[qb + j], z##j = z_lds[qb + j];
    LIST16(DECLC)
    #define PINC(j) asm volatile("" : "+v"(x##j), "+v"(y##j), "+v"(z##j));
    LIST16(PINC)
    #define DECLD(j) float d##j = BIGDIST;
    LIST16(DECLD)

    // initial centroid = point 0 of this batch
    float cx = base[0], cy = base[1], cz = base[2];
    if (w == 0 && tid == 0) out[b * npoint + 0] = 0;

    const size_t PAR = (size_t)NBATCH * WGB * SLOT_STRIDE;   // parity block (u64s)
    u64* sbase = slots + (size_t)b * WGB * SLOT_STRIDE;

    for (int i = 0; i < npoint - 1; ++i) {
        // ---- distance min-update + per-lane argmax (pure register VALU) ----
        float bv = -1.0f; int bj = 0;
        {
            #pragma clang fp contract(off)
            #define UPD(j) { float dx = x##j - cx, dy = y##j - cy, dz = z##j - cz; \
                             float dd = dx*dx + dy*dy + dz*dz;  /* matches np ref */ \
                             float nd = fminf(d##j, dd); d##j = nd;                  \
                             if (nd > bv) { bv = nd; bj = j; } } /* strict >: first max */
            LIST16(UPD)
        }
        // pack: [63:32] val bits (non-neg -> order-preserving)
        //       [16:0]  131071 - idx (bigger packed == smaller idx on tie)
        //       [31:22] tag added at publish
        u64 pk = ((u64)__float_as_uint(bv) << 32)
               | (u64)(0x1FFFFu - (unsigned)(pbase + bj));

        #pragma unroll
        for (int m = 32; m >= 1; m >>= 1) {
            u64 o = __shfl_xor(pk, m);
            if (o > pk) pk = o;
        }
        if (lane == 0) s_w[v] = pk;
        __syncthreads();

        u64* sb = sbase + ((i & 1) ? PAR : (size_t)0);
        const unsigned tag = (unsigned)(i + 1);   // 1..1023, 10 bits, never 0

        if (v == 0) {
            // ---- combine the 4 wave partials (all lanes end with WG best) ----
            u64 c = s_w[lane & 3];
            u64 o1 = __shfl_xor(c, 1); if (o1 > c) c = o1;
            u64 o2 = __shfl_xor(c, 2); if (o2 > c) c = o2;

            // ---- lane 0: look up candidate coords in LDS, publish 4 words ----
            if (lane == 0) {
                int idx_wg = (int)(0x1FFFFu - (unsigned)(c & 0x1FFFFu));
                int qw = idx_wg - q0;                      // 0..4095, ours
                u64 tw = ((u64)tag << 32);
                u64* my = sb + (size_t)w * SLOT_STRIDE;
                __hip_atomic_store(my + 1, tw | (u64)__float_as_uint(x_lds[qw]),
                                   __ATOMIC_RELAXED, __HIP_MEMORY_SCOPE_AGENT);
                __hip_atomic_store(my + 2, tw | (u64)__float_as_uint(y_lds[qw]),
                                   __ATOMIC_RELAXED, __HIP_MEMORY_SCOPE_AGENT);
                __hip_atomic_store(my + 3, tw | (u64)__float_as_uint(z_lds[qw]),
                                   __ATOMIC_RELAXED, __HIP_MEMORY_SCOPE_AGENT);
                __hip_atomic_store(my + 0, c | ((u64)tag << 22),
                                   __ATOMIC_RELAXED, __HIP_MEMORY_SCOPE_AGENT);
            }

            // ---- poll: lane pair (2s, 2s+1) covers slot s; even lane reads
            //      words 0,1 ; odd lane reads words 2,3. Every word self-tagged.
            const int  s    = lane >> 1;
            const bool even = (lane & 1) == 0;
            u64* sp = sb + (size_t)s * SLOT_STRIDE + (even ? 0 : 2);
            u64 wa = 0, wb = 0;
            bool oka = false, okb = false;
            do {
                if (!oka) {
                    wa = __hip_atomic_load(sp + 0, __ATOMIC_RELAXED,
                                           __HIP_MEMORY_SCOPE_AGENT);
                    unsigned t = even ? (unsigned)((wa >> 22) & 1023u)
                                      : (unsigned)((wa >> 32) & 1023u);
                    oka = (t == tag);
                }
                if (!okb) {
                    wb = __hip_atomic_load(sp + 1, __ATOMIC_RELAXED,
                                           __HIP_MEMORY_SCOPE_AGENT);
                    okb = ((unsigned)((wb >> 32) & 1023u) == tag);
                }
            } while (__ballot(oka && okb) != ~0ULL);

            // ---- butterfly max over word0 (even lanes carry candidates) ----
            u64 mx = even ? wa : 0;     // word0 >= tag<<22 > 0, so 0 never wins
            #pragma unroll
            for (int m = 32; m >= 1; m >>= 1) {
                u64 o = __shfl_xor(mx, m);
                if (o > mx) mx = o;
            }
            int idx_win = (int)(0x1FFFFu - (unsigned)(mx & 0x1FFFFu));
            int sw = idx_win >> 12;                  // winner slot = idx / 4096

            // coords: even lane 2sw holds x (wb=word1); odd 2sw+1 holds y,z
            float fx = even ? __uint_as_float((unsigned)wb) : 0.f;
            float fy = even ? 0.f : __uint_as_float((unsigned)wa);
            float fz = even ? 0.f : __uint_as_float((unsigned)wb);
            float nx = __shfl(fx, 2 * sw);
            float ny = __shfl(fy, 2 * sw + 1);
            float nz = __shfl(fz, 2 * sw + 1);
            if (lane == 0) {
                s_c[0] = nx; s_c[1] = ny; s_c[2] = nz; s_f = idx_win;
            }
        }
        __syncthreads();

        cx = s_c[0]; cy = s_c[1]; cz = s_c[2];
        if (w == 0 && tid == 0) out[b * npoint + (i + 1)] = s_f;
    }
}

extern "C" void kernel_launch(void* const* d_in, const int* in_sizes, int n_in,
                              void* d_out, int out_size, void* d_ws, size_t ws_size,
                              hipStream_t stream) {
    const float* xyz = (const float*)d_in[0];
    int* out = (int*)d_out;
    u64* slots = (u64*)d_ws;
    const int npoint = out_size / NBATCH;   // 1024

    // Clear slot region (64 KB) so stale/poisoned tags can never match tag>=1.
    hipMemsetAsync(d_ws, 0,
                   (size_t)2 * NBATCH * WGB * SLOT_STRIDE * sizeof(u64),
                   stream);

    dim3 grid(NBATCH * WGB);   // 256 WGs <= 256 CUs -> all co-resident, spin-sync safe
    dim3 block(THREADS);
    fps_kernel<<<grid, block, 0, stream>>>(xyz, out, slots, npoint);
}

// Round 8
// 2383.935 us; speedup vs baseline: 1.2833x; 1.2135x over previous
//
#include <hip/hip_runtime.h>
#include <stdint.h>

// Farthest Point Sampling, B=8, N=131072, npoint=1024.
// 8 batches x 32 WGs x 256 threads (all 256 CUs). r5 structure (LDS coords,
// WG-slots, wave0 polls, 2 barriers/iter) with ONE change: the per-iteration
// sync runs at XCD-L2 latency instead of DRAM latency.
//   Evidence: r5 FETCH_SIZE 36MB == slot working set x 1023 iters -> agent-
//   scope slot atomics are DRAM-serviced (~0.9us/poll RT) = the 1.8us/iter floor.
//   Fix: batch b's 32 WGs sit on one XCD (bid&7 under round-robin dispatch);
//   within an XCD the L2 IS coherent and no-sc-bit atomic RMWs execute at L2.
//   A one-time CENSUS (s_getreg HW_REG_XCC_ID, published via the proven
//   agent-scope protocol) verifies co-residency per batch; only then is the
//   WORKGROUP-scope (L2-point) publish/poll used, else r5's agent-scope path.
//   Correctness therefore never depends on the undefined WG->XCD mapping.

#define NPTS        131072
#define NBATCH      8
#define WGB         32          // workgroups per batch
#define THREADS     256
#define PPW         4096        // points per WG
#define SLOT_STRIDE 16          // u64s per slot = 128 B (own cache line)
#define BIGDIST     1e10f

typedef unsigned long long u64;

__global__ __launch_bounds__(THREADS, 1) void fps_kernel(
        const float* __restrict__ xyz,   // [B, N, 3]
        int* __restrict__ out,           // [B, npoint]
        u64* __restrict__ ws,            // slots + census
        int npoint)
{
    const int bid  = blockIdx.x;
    const int b    = bid & (NBATCH - 1);  // batch; its 32 WGs on one XCD (verified!)
    const int w    = bid >> 3;            // 0..31 WG-within-batch
    const int tid  = threadIdx.x;
    const int lane = tid & 63;
    const int v    = tid >> 6;            // wave 0..3

    const float* base = xyz + (size_t)b * NPTS * 3;
    const int q0 = w * PPW;               // first batch-point of this WG

    __shared__ __align__(16) float x_lds[PPW];
    __shared__ __align__(16) float y_lds[PPW];
    __shared__ __align__(16) float z_lds[PPW];
    __shared__ u64   s_w[THREADS / 64];
    __shared__ float s_c[3];
    __shared__ int   s_f;
    __shared__ int   s_fast;

    // ---- one-time fill: thread t loads points t+256j (conflict-free, r5) ----
    #pragma unroll
    for (int j = 0; j < 16; ++j) {
        int q = tid + 256 * j;                      // 0..4095 within WG
        const float* p = base + (size_t)(q0 + q) * 3;
        x_lds[q] = p[0];
        y_lds[q] = p[1];
        z_lds[q] = p[2];
    }

    u64* slots  = ws;                                        // [2][NB][WGB][STRIDE]
    u64* census = ws + (size_t)2 * NBATCH * WGB * SLOT_STRIDE; // [NB][WGB][STRIDE]

    // ---- census: verify all 32 WGs of this batch share an XCD (wave 0) ----
    if (v == 0) {
        unsigned xcc;
        asm volatile("s_getreg_b32 %0, hwreg(HW_REG_XCC_ID)" : "=s"(xcc));
        u64* cb = census + (size_t)b * WGB * SLOT_STRIDE;
        if (lane == 0) {
            __hip_atomic_store(cb + (size_t)w * SLOT_STRIDE,
                               (0xC0DEC0DEull << 32) | (u64)xcc,
                               __ATOMIC_RELAXED, __HIP_MEMORY_SCOPE_AGENT);
        }
        u64 cv = 0;
        if (lane < WGB) {
            u64* cl = cb + (size_t)lane * SLOT_STRIDE;
            do {
                cv = __hip_atomic_load(cl, __ATOMIC_RELAXED,
                                       __HIP_MEMORY_SCOPE_AGENT);
            } while ((cv >> 32) != 0xC0DEC0DEull);
        }
        unsigned my = (unsigned)cv;
        unsigned x0 = __shfl(my, 0);
        bool same = (lane >= WGB) || (my == x0);
        if (lane == 0) s_fast = (__ballot(same) == ~0ull) ? 1 : 0;
    }

    float dist[16];
    #pragma unroll
    for (int j = 0; j < 16; ++j) dist[j] = BIGDIST;

    float cx = base[0], cy = base[1], cz = base[2];   // centroid 0 = point 0
    if (w == 0 && tid == 0) out[b * npoint + 0] = 0;

    __syncthreads();   // fill + census visible to all waves
    const int fast = s_fast;

    const size_t PAR = (size_t)NBATCH * WGB * SLOT_STRIDE;   // parity block (u64s)
    u64* sbase = slots + (size_t)b * WGB * SLOT_STRIDE;

    for (int i = 0; i < npoint - 1; ++i) {
        // ---- distance min-update + per-thread argmax (LDS b128 + VALU, r5) ----
        float bv = -1.0f; int bq = 0;   // bq: point index within WG (0..4095)
        {
            #pragma clang fp contract(off)
            #pragma unroll
            for (int g = 0; g < 4; ++g) {
                const int qg = 4 * tid + 1024 * g;
                float4 xv = *reinterpret_cast<const float4*>(&x_lds[qg]);
                float4 yv = *reinterpret_cast<const float4*>(&y_lds[qg]);
                float4 zv = *reinterpret_cast<const float4*>(&z_lds[qg]);
                float xs[4] = { xv.x, xv.y, xv.z, xv.w };
                float ys[4] = { yv.x, yv.y, yv.z, yv.w };
                float zs[4] = { zv.x, zv.y, zv.z, zv.w };
                #pragma unroll
                for (int e = 0; e < 4; ++e) {
                    const int j = 4 * g + e;
                    float dx = xs[e] - cx, dy = ys[e] - cy, dz = zs[e] - cz;
                    float d  = dx*dx + dy*dy + dz*dz;   // mul/add order matches np ref
                    float nd = fminf(dist[j], d);
                    dist[j]  = nd;
                    if (nd > bv) { bv = nd; bq = qg + e; }  // strict >: first max
                }
            }
        }
        // pack: [63:32] val bits (non-neg -> order-preserving)
        //       [16:0]  131071 - idx (bigger packed == smaller idx on tie)
        //       [31:22] tag added at publish
        u64 pk = ((u64)__float_as_uint(bv) << 32)
               | (u64)(0x1FFFFu - (unsigned)(q0 + bq));

        #pragma unroll
        for (int m = 32; m >= 1; m >>= 1) {
            u64 o = __shfl_xor(pk, m);
            if (o > pk) pk = o;
        }
        if (lane == 0) s_w[v] = pk;
        __syncthreads();

        u64* sb = sbase + ((i & 1) ? PAR : (size_t)0);
        const unsigned tag = (unsigned)(i + 1);   // 1..1023, 10 bits, never 0

        if (v == 0) {
            // ---- combine the 4 wave partials ----
            u64 c = s_w[lane & 3];
            u64 o1 = __shfl_xor(c, 1); if (o1 > c) c = o1;
            u64 o2 = __shfl_xor(c, 2); if (o2 > c) c = o2;

            // ---- publish WG winner ----
            if (lane == 0) {
                u64 pub = c | ((u64)tag << 22);
                u64* my = sb + (size_t)w * SLOT_STRIDE;
                if (fast) {
                    // RMW executes at the (shared, coherent) XCD L2
                    __hip_atomic_exchange(my, pub, __ATOMIC_RELAXED,
                                          __HIP_MEMORY_SCOPE_WORKGROUP);
                } else {
                    __hip_atomic_store(my, pub, __ATOMIC_RELAXED,
                                       __HIP_MEMORY_SCOPE_AGENT);
                }
            }

            // ---- poll all 32 slots (lane s covers slot s) ----
            u64 s = 0;
            if (lane < WGB) {
                u64* sl = sb + (size_t)lane * SLOT_STRIDE;
                if (fast) {
                    do {   // RMW poll: executes at L2, can't read stale L1
                        s = __hip_atomic_fetch_or(sl, 0ull, __ATOMIC_RELAXED,
                                                  __HIP_MEMORY_SCOPE_WORKGROUP);
                    } while (((unsigned)(s >> 22) & 1023u) != tag);
                } else {
                    do {
                        s = __hip_atomic_load(sl, __ATOMIC_RELAXED,
                                              __HIP_MEMORY_SCOPE_AGENT);
                    } while (((unsigned)(s >> 22) & 1023u) != tag);
                }
            }
            // speculative candidate-coords fetch (L2-local on fast path)
            int idx_l = (int)(0x1FFFFu - (unsigned)(s & 0x1FFFFu));
            float ccx = 0.f, ccy = 0.f, ccz = 0.f;
            if (lane < WGB) {
                const float* cp = base + (size_t)idx_l * 3;
                ccx = cp[0]; ccy = cp[1]; ccz = cp[2];
            }
            // ---- butterfly max over the 32 slot values ----
            u64 mx = s;
            #pragma unroll
            for (int m = 32; m >= 1; m >>= 1) {
                u64 o = __shfl_xor(mx, m);
                if (o > mx) mx = o;
            }
            u64 ball = __ballot(lane < WGB && s == mx);
            int winlane = __ffsll(ball) - 1;
            float wx = __shfl(ccx, winlane);
            float wy = __shfl(ccy, winlane);
            float wz = __shfl(ccz, winlane);
            int  wix = __shfl(idx_l, winlane);
            if (lane == 0) {
                s_c[0] = wx; s_c[1] = wy; s_c[2] = wz; s_f = wix;
                if (w == 0) out[b * npoint + (i + 1)] = wix;
            }
        }
        __syncthreads();

        cx = s_c[0]; cy = s_c[1]; cz = s_c[2];
    }
}

extern "C" void kernel_launch(void* const* d_in, const int* in_sizes, int n_in,
                              void* d_out, int out_size, void* d_ws, size_t ws_size,
                              hipStream_t stream) {
    const float* xyz = (const float*)d_in[0];
    int* out = (int*)d_out;
    u64* ws = (u64*)d_ws;
    const int npoint = out_size / NBATCH;   // 1024

    // Clear slots (64 KB) + census (32 KB): stale/poisoned tags can never match.
    hipMemsetAsync(d_ws, 0,
                   (size_t)(2 * NBATCH * WGB + NBATCH * WGB) * SLOT_STRIDE * sizeof(u64),
                   stream);

    dim3 grid(NBATCH * WGB);   // 256 WGs <= 256 CUs -> all co-resident, spin-sync safe
    dim3 block(THREADS);
    fps_kernel<<<grid, block, 0, stream>>>(xyz, out, ws, npoint);
}